// Round 4
// baseline (4966.066 us; speedup 1.0000x reference)
//
#include <hip/hip_runtime.h>
#include <hip/hip_bf16.h>
#include <hip/hip_cooperative_groups.h>

namespace cg = cooperative_groups;

// Problem constants
#define NB 1024      // batch
#define NT 120       // seq len
#define NE 50        // embed
#define NH 300       // hidden
#define KXP 64       // padded x K (k-chunks 0..1)
#define KHP 320      // padded h K / h row stride (k-chunks 2..11)
#define KT 384       // total padded K (12 chunks of 32)
#define HPAD 320     // padded cols per gate in Wp (10 groups of 32)
#define WCH 48       // KT/8 bf16x8 chunks per W column
#define NRG 16       // row groups of 64 batch rows
#define NCG 10       // col groups of 32 hidden cols
#define NGB 160      // GEMM blocks = NRG*NCG
#define NAUX 32      // aux blocks (x-stage + preds), 32 rows each
#define NBLKS 192

typedef __bf16 bf16_t;
typedef __bf16 bf16x8 __attribute__((ext_vector_type(8)));
typedef __bf16 bf16x2 __attribute__((ext_vector_type(2)));
typedef float f32x4 __attribute__((ext_vector_type(4)));

__device__ __forceinline__ float sigmoidf_(float x) { return 1.0f / (1.0f + __expf(-x)); }
__device__ __forceinline__ float tanhf_(float x) {
    return 1.0f - 2.0f / (__expf(2.0f * x) + 1.0f);
}

// Wp[col][k]: col = g*HPAD + hc. k map: k<50 -> W[k] (x rows); 50..63 -> 0;
// 64..363 -> W[k-14] (h rows 50..349); 364..383 -> 0.  (validated in round 2)
__global__ void prep_w(const float* __restrict__ W, bf16_t* __restrict__ Wp) {
    int gid = blockIdx.x * 256 + threadIdx.x;
    if (gid >= 4 * HPAD * KT) return;
    int k = gid % KT;
    int col = gid / KT;
    int g = col / HPAD, hc = col % HPAD;
    int kp = -1;
    if (k < 50) kp = k;
    else if (k >= 64 && k < 364) kp = k - 14;
    float v = 0.0f;
    if (kp >= 0 && hc < NH) v = W[(long)kp * 1200 + g * NH + hc];
    Wp[gid] = (bf16_t)v;
}

__global__ void prep_zero(uint4* __restrict__ p, int n) {
    int gid = blockIdx.x * 256 + threadIdx.x;
    if (gid < n) p[gid] = make_uint4(0u, 0u, 0u, 0u);
}

// Stage x_0 into Xb0: row-major 1024 x 64 bf16 (cols 50..63 zero)
__global__ void prep_x0(const int* __restrict__ ids, const float* __restrict__ emb,
                        bf16_t* __restrict__ Xb0) {
    int gid = blockIdx.x * 256 + threadIdx.x;
    if (gid >= NB * KXP) return;
    int row = gid >> 6, c = gid & 63;
    int id = ids[row * NT + 0];
    Xb0[gid] = (bf16_t)((c < NE) ? emb[(long)id * NE + c] : 0.0f);
}

// Cooperative persistent kernel, one grid.sync per timestep.
// Blocks 0..159: GEMM, 64 rows x 32 cols x 4 gates; c persistent in VGPRs.
// Blocks 160..191: stage x_{t+1} into Xb[(t+1)&1]; preds[t-1] from Hr.
__global__ void __launch_bounds__(256, 2) lstm_coop(
    const int* __restrict__ ids, const float* __restrict__ emb,
    const float* __restrict__ bl, const bf16_t* __restrict__ Wp,
    const float* __restrict__ U, const float* __restrict__ b2,
    bf16_t* __restrict__ H0, bf16_t* __restrict__ H1,
    bf16_t* __restrict__ Xb0, bf16_t* __restrict__ Xb1,
    float* __restrict__ out)
{
    cg::grid_group grid = cg::this_grid();
    const int blk = blockIdx.x, tid = threadIdx.x;

    if (blk < NGB) {
        const int rowGroup = blk / NCG;
        const int colGroup = blk % NCG;
        const int wave = tid >> 6, lane = tid & 63;
        const int m = lane & 15, quad = lane >> 4;
        const int rowBase = rowGroup * 64 + wave * 16;
        const int myRow = rowBase + m;

        int colv[2]; bool cok[2]; int bb[2][4]; float bias[2][4];
        f32x4 creg[2];
#pragma unroll
        for (int ct = 0; ct < 2; ++ct) {
            int col = colGroup * 32 + ct * 16 + m;     // < 320
            colv[ct] = col;
            cok[ct] = (col < NH);
#pragma unroll
            for (int g = 0; g < 4; ++g) {
                bb[ct][g] = (g * HPAD + col) * WCH;
                bias[ct][g] = cok[ct] ? bl[g * NH + col] : 0.f;
            }
            creg[ct] = (f32x4){0.f, 0.f, 0.f, 0.f};
        }

        const bf16x8* Wv = (const bf16x8*)Wp;

        for (int t = 0; t < NT; ++t) {
            const bf16_t* Xc = (t & 1) ? Xb1 : Xb0;
            const bf16_t* Hr = (t & 1) ? H1 : H0;
            bf16_t* Hw       = (t & 1) ? H0 : H1;

            const bf16x8* Ax = (const bf16x8*)(Xc + (long)myRow * KXP);
            const bf16x8* Ah = (const bf16x8*)(Hr + (long)myRow * KHP);

            bf16x8 af[12];
#pragma unroll
            for (int kk = 0; kk < 2; ++kk)  af[kk] = Ax[kk * 4 + quad];
#pragma unroll
            for (int kk = 2; kk < 12; ++kk) af[kk] = Ah[(kk - 2) * 4 + quad];

            f32x4 acc[2][4];
#pragma unroll
            for (int ct = 0; ct < 2; ++ct)
#pragma unroll
                for (int g = 0; g < 4; ++g) acc[ct][g] = (f32x4){0.f, 0.f, 0.f, 0.f};

#pragma unroll
            for (int kk = 0; kk < 12; ++kk) {
#pragma unroll
                for (int ct = 0; ct < 2; ++ct)
#pragma unroll
                    for (int g = 0; g < 4; ++g)
                        acc[ct][g] = __builtin_amdgcn_mfma_f32_16x16x32_bf16(
                            af[kk], Wv[bb[ct][g] + kk * 4 + quad], acc[ct][g], 0, 0, 0);
            }

            // C/D: col = lane&15, row = quad*4 + r (validated rounds 2-3)
#pragma unroll
            for (int ct = 0; ct < 2; ++ct) {
#pragma unroll
                for (int r = 0; r < 4; ++r) {
                    float zi = acc[ct][0][r] + bias[ct][0];
                    float zj = acc[ct][1][r] + bias[ct][1];
                    float zf = acc[ct][2][r] + bias[ct][2];
                    float zo = acc[ct][3][r] + bias[ct][3];
                    float cn = creg[ct][r] * sigmoidf_(zf + 1.0f)
                             + sigmoidf_(zi) * tanhf_(zj);
                    creg[ct][r] = cn;
                    float hn = tanhf_(cn) * sigmoidf_(zo);
                    if (cok[ct])
                        Hw[(long)(rowBase + quad * 4 + r) * KHP + colv[ct]] = (bf16_t)hn;
                }
            }
            grid.sync();
        }
    } else {
        const int a = blk - NGB;
        const int r0 = a * 32;                 // 32 batch rows per aux block
        const int prow = r0 + tid / 5;         // preds task (tid < 160)
        const int pcls = tid % 5;

        for (int t = 0; t < NT; ++t) {
            const bf16_t* Hr = (t & 1) ? H1 : H0;     // holds h_{t-1}
            bf16_t* Xn       = (t & 1) ? Xb0 : Xb1;   // x_{t+1} destination

            if (t >= 1 && tid < 160) {
                const bf16_t* hrow = Hr + (long)prow * KHP;
                float s = 0.f;
#pragma unroll 4
                for (int c = 0; c < NH; c += 2) {
                    bf16x2 h2 = *(const bf16x2*)(hrow + c);
                    s += (float)h2[0] * U[c * 5 + pcls]
                       + (float)h2[1] * U[(c + 1) * 5 + pcls];
                }
                out[(long)(t - 1) * (NB * 5) + prow * 5 + pcls] = s + b2[pcls];
            }
            if (t + 1 < NT) {
                for (int s = tid; s < 32 * KXP; s += 256) {
                    int row = s >> 6, c = s & 63;
                    int id = ids[(r0 + row) * NT + (t + 1)];
                    float v = (c < NE) ? emb[(long)id * NE + c] : 0.0f;
                    Xn[(long)(r0 + row) * KXP + c] = (bf16_t)v;
                }
            }
            grid.sync();
        }
        // preds[NT-1]: h_{119} is in H0 (last write of t=119)
        if (tid < 160) {
            const bf16_t* hrow = H0 + (long)prow * KHP;
            float s = 0.f;
#pragma unroll 4
            for (int c = 0; c < NH; c += 2) {
                bf16x2 h2 = *(const bf16x2*)(hrow + c);
                s += (float)h2[0] * U[c * 5 + pcls]
                   + (float)h2[1] * U[(c + 1) * 5 + pcls];
            }
            out[(long)(NT - 1) * (NB * 5) + prow * 5 + pcls] = s + b2[pcls];
        }
    }
}

extern "C" void kernel_launch(void* const* d_in, const int* in_sizes, int n_in,
                              void* d_out, int out_size, void* d_ws, size_t ws_size,
                              hipStream_t stream) {
    const int* ids   = (const int*)d_in[0];
    const float* emb = (const float*)d_in[1];
    const float* W   = (const float*)d_in[2];
    const float* bl  = (const float*)d_in[3];
    const float* U   = (const float*)d_in[4];
    const float* b2  = (const float*)d_in[5];
    float* out = (float*)d_out;

    // ws layout (2,555,904 B total; round 2 proved >= 3.4 MB available):
    char* ws = (char*)d_ws;
    bf16_t* Wp  = (bf16_t*)ws;                    // 4*320*384*2 = 983,040 B
    bf16_t* H0  = (bf16_t*)(ws + 983040);         // 1024*320*2  = 655,360 B
    bf16_t* H1  = (bf16_t*)(ws + 1638400);        // 655,360 B
    bf16_t* Xb0 = (bf16_t*)(ws + 2293760);        // 1024*64*2   = 131,072 B
    bf16_t* Xb1 = (bf16_t*)(ws + 2424832);        // 131,072 B

    prep_w<<<(4 * HPAD * KT + 255) / 256, 256, 0, stream>>>(W, Wp);
    int nzero = (2 * NB * KHP * 2) / 16;          // H0+H1 contiguous
    prep_zero<<<(nzero + 255) / 256, 256, 0, stream>>>((uint4*)H0, nzero);
    prep_x0<<<(NB * KXP + 255) / 256, 256, 0, stream>>>(ids, emb, Xb0);

    void* args[11];
    args[0] = (void*)&ids;  args[1] = (void*)&emb;  args[2] = (void*)&bl;
    args[3] = (void*)&Wp;   args[4] = (void*)&U;    args[5] = (void*)&b2;
    args[6] = (void*)&H0;   args[7] = (void*)&H1;
    args[8] = (void*)&Xb0;  args[9] = (void*)&Xb1;  args[10] = (void*)&out;
    hipLaunchCooperativeKernel((void*)lstm_coop, dim3(NBLKS), dim3(256),
                               args, 0, stream);
}

// Round 5
// 3558.284 us; speedup vs baseline: 1.3956x; 1.3956x over previous
//
#include <hip/hip_runtime.h>
#include <hip/hip_bf16.h>

// Problem constants
#define NB 1024      // batch
#define NT 120       // seq len
#define NE 50        // embed (A cols 0..49)
#define NH 300       // hidden (A cols 50..349)
#define KP 352       // padded K (x 50 + h 300 + 2 pad); 11 chunks of 32
#define KCH 11       // K chunks
#define AST 360      // LDS A-row stride in bf16 (720 B -> conflict-free-ish)
#define NTILE 19     // 16-wide col tiles (304 padded cols per gate)
#define NTG 76       // tile-gate pairs = NTILE*4
#define NBLK 64      // 64 blocks, 16 batch rows each, sync-free persistent
#define NROWS 16
#define PKCH 10      // preds K chunks (h padded to 320)
#define ABUFSZ (NROWS * AST + 32)   // +32 tail pad for preds overread

typedef __bf16 bf16_t;
typedef __bf16 bf16x8 __attribute__((ext_vector_type(8)));
typedef float f32x4 __attribute__((ext_vector_type(4)));

__device__ __forceinline__ float sigmoidf_(float x) { return 1.0f / (1.0f + __expf(-x)); }
__device__ __forceinline__ float tanhf_(float x) {
    return 1.0f - 2.0f / (__expf(2.0f * x) + 1.0f);
}

// Fragment-order W: Wf[((tg*KCH + kk)*64 + lane)*8 + j]
//   tg = tile*4 + gate; lane = quad*16 + m; value = W[k][g*300 + hc]
//   hc = tile*16 + m, k = kk*32 + quad*8 + j  (k<350; W rows are [x(50);h(300)])
__global__ void prep_wf(const float* __restrict__ W, bf16_t* __restrict__ Wf) {
    int gid = blockIdx.x * 256 + threadIdx.x;
    if (gid >= NTG * KCH * 512) return;
    int j = gid & 7;
    int lane = (gid >> 3) & 63;
    int kk = (gid >> 9) % KCH;
    int tg = gid / (KCH * 512);
    int m = lane & 15, quad = lane >> 4;
    int ti = tg >> 2, g = tg & 3;
    int hc = ti * 16 + m;
    int k = kk * 32 + quad * 8 + j;
    float v = (k < 350 && hc < NH) ? W[(long)k * 1200 + g * NH + hc] : 0.0f;
    Wf[gid] = (bf16_t)v;
}

// Fragment-order U^T: Uf[(kk*64 + lane)*8 + j] = U[c*5 + m] for m<5, c = kk*32+quad*8+j
__global__ void prep_uf(const float* __restrict__ U, bf16_t* __restrict__ Uf) {
    int gid = blockIdx.x * 256 + threadIdx.x;
    if (gid >= PKCH * 512) return;
    int j = gid & 7;
    int lane = (gid >> 3) & 63;
    int kk = gid >> 9;
    int m = lane & 15, quad = lane >> 4;
    int c = kk * 32 + quad * 8 + j;
    float v = (m < 5 && c < NH) ? U[c * 5 + m] : 0.0f;
    Uf[gid] = (bf16_t)v;
}

// Sync-free persistent LSTM: block = 16 batch rows for all 120 steps.
// A ping-pong in LDS: row = [x_t(50) | h_{t-1}(300) | pad]; c in VGPRs.
// Waves 0-2: 5 col-tiles x 4 gates. Wave 3: 4 tiles + preds[t-1] (MFMA).
// Wave 2 additionally stages x_{t+1}. One __syncthreads per step; zero
// cross-block traffic -> W stays L2-resident for the whole kernel.
__global__ void __launch_bounds__(256, 1) lstm_persist2(
    const int* __restrict__ ids, const float* __restrict__ emb,
    const float* __restrict__ bl, const bf16_t* __restrict__ Wf,
    const bf16_t* __restrict__ Uf, const float* __restrict__ b2,
    float* __restrict__ out)
{
    __shared__ bf16_t Abuf[2 * ABUFSZ];
    const int tid = threadIdx.x, blk = blockIdx.x;
    const int wave = tid >> 6, lane = tid & 63;
    const int m = lane & 15, quad = lane >> 4;
    const int row0 = blk * NROWS;

    // zero both LDS buffers (h_0 = 0; pads harmless vs zero W rows)
    for (int i = tid; i < 2 * ABUFSZ; i += 256) Abuf[i] = (bf16_t)0.0f;
    __syncthreads();
    // stage x_0 into buffer 0
    {
        int r = tid >> 4, seg = tid & 15;
        int id = ids[(row0 + r) * NT + 0];
        const float* er = emb + (long)id * NE;
#pragma unroll
        for (int j = 0; j < 4; ++j) {
            int c = seg * 4 + j;
            if (c < NE) Abuf[r * AST + c] = (bf16_t)er[c];
        }
    }
    __syncthreads();

    const int ntw = (wave < 3) ? 5 : 4;
    int colv[5]; bool cok[5]; float bias[5][4]; float creg[5][4];
    long wb[5][4];
#pragma unroll
    for (int ti = 0; ti < 5; ++ti) {
        int tig = wave * 5 + ti;                  // wave3 uses 15..18
        if (tig > 18) tig = 18;                   // clamp (unused lanes)
        int col = tig * 16 + m;
        colv[ti] = col;
        cok[ti] = (col < NH) && (ti < ntw);
#pragma unroll
        for (int g = 0; g < 4; ++g) {
            wb[ti][g] = ((long)(tig * 4 + g) * KCH * 512) + lane * 8;
            bias[ti][g] = cok[ti] ? bl[g * NH + col] : 0.f;
        }
#pragma unroll
        for (int r = 0; r < 4; ++r) creg[ti][r] = 0.f;
    }
    const float pb2 = (m < 5) ? b2[m] : 0.f;      // preds bias (wave 3)

    for (int t = 0; t < NT; ++t) {
        const bf16_t* Ac = Abuf + (t & 1) * ABUFSZ;
        bf16_t* An       = Abuf + ((t + 1) & 1) * ABUFSZ;

        // A fragments: A[row=m][k = kk*32 + quad*8 + j]
        bf16x8 af[KCH];
        const bf16_t* Arow = Ac + m * AST;
#pragma unroll
        for (int kk = 0; kk < KCH; ++kk)
            af[kk] = *(const bf16x8*)(Arow + kk * 32 + quad * 8);

#pragma unroll
        for (int ti = 0; ti < 5; ++ti) {
            if (ti < ntw) {
                f32x4 acc[4];
#pragma unroll
                for (int g = 0; g < 4; ++g) acc[g] = (f32x4){0.f, 0.f, 0.f, 0.f};
#pragma unroll
                for (int kk = 0; kk < KCH; ++kk) {
#pragma unroll
                    for (int g = 0; g < 4; ++g)
                        acc[g] = __builtin_amdgcn_mfma_f32_16x16x32_bf16(
                            af[kk],
                            *(const bf16x8*)(Wf + wb[ti][g] + (long)kk * 512),
                            acc[g], 0, 0, 0);
                }
                // C/D: col = lane&15, row = quad*4 + r (validated rounds 2-4)
#pragma unroll
                for (int r = 0; r < 4; ++r) {
                    float zi = acc[0][r] + bias[ti][0];
                    float zj = acc[1][r] + bias[ti][1];
                    float zf = acc[2][r] + bias[ti][2];
                    float zo = acc[3][r] + bias[ti][3];
                    float cn = creg[ti][r] * sigmoidf_(zf + 1.0f)
                             + sigmoidf_(zi) * tanhf_(zj);
                    creg[ti][r] = cn;
                    float hn = tanhf_(cn) * sigmoidf_(zo);
                    if (cok[ti])
                        An[(quad * 4 + r) * AST + NE + colv[ti]] = (bf16_t)hn;
                }
            }
        }

        if (wave == 3) {
            // preds[t-1] = h_{t-1} @ U + b2 via MFMA (h_{t-1} = Ac h-region)
            if (t >= 1) {
                f32x4 pacc = (f32x4){0.f, 0.f, 0.f, 0.f};
#pragma unroll
                for (int kk = 0; kk < PKCH; ++kk) {
                    bf16x8 ah = *(const bf16x8*)(Arow + NE + kk * 32 + quad * 8);
                    pacc = __builtin_amdgcn_mfma_f32_16x16x32_bf16(
                        ah, *(const bf16x8*)(Uf + kk * 512 + lane * 8), pacc, 0, 0, 0);
                }
                if (m < 5) {
                    float* op = out + (long)(t - 1) * (NB * 5)
                              + (row0 + quad * 4) * 5 + m;
                    op[0]  = pacc[0] + pb2;
                    op[5]  = pacc[1] + pb2;
                    op[10] = pacc[2] + pb2;
                    op[15] = pacc[3] + pb2;
                }
            }
        } else if (wave == 2) {
            // stage x_{t+1} into An's x region
            if (t + 1 < NT) {
                int r = lane >> 2, p = lane & 3;
                int id = ids[(row0 + r) * NT + (t + 1)];
                const float* er = emb + (long)id * NE;
                for (int c = p; c < NE; c += 4)
                    An[r * AST + c] = (bf16_t)er[c];
            }
        }
        __syncthreads();
    }

    // preds[NT-1] from buffer (NT&1) = buffer 0
    if (wave == 3) {
        const bf16_t* Ac = Abuf + (NT & 1) * ABUFSZ;
        const bf16_t* Arow = Ac + m * AST;
        f32x4 pacc = (f32x4){0.f, 0.f, 0.f, 0.f};
#pragma unroll
        for (int kk = 0; kk < PKCH; ++kk) {
            bf16x8 ah = *(const bf16x8*)(Arow + NE + kk * 32 + quad * 8);
            pacc = __builtin_amdgcn_mfma_f32_16x16x32_bf16(
                ah, *(const bf16x8*)(Uf + kk * 512 + lane * 8), pacc, 0, 0, 0);
        }
        if (m < 5) {
            float* op = out + (long)(NT - 1) * (NB * 5) + (row0 + quad * 4) * 5 + m;
            op[0]  = pacc[0] + pb2;
            op[5]  = pacc[1] + pb2;
            op[10] = pacc[2] + pb2;
            op[15] = pacc[3] + pb2;
        }
    }
}

extern "C" void kernel_launch(void* const* d_in, const int* in_sizes, int n_in,
                              void* d_out, int out_size, void* d_ws, size_t ws_size,
                              hipStream_t stream) {
    const int* ids   = (const int*)d_in[0];
    const float* emb = (const float*)d_in[1];
    const float* W   = (const float*)d_in[2];
    const float* bl  = (const float*)d_in[3];
    const float* U   = (const float*)d_in[4];
    const float* b2  = (const float*)d_in[5];
    float* out = (float*)d_out;

    // ws: Wf 856,064 B + Uf 10,240 B
    char* ws = (char*)d_ws;
    bf16_t* Wf = (bf16_t*)ws;
    bf16_t* Uf = (bf16_t*)(ws + 856064);

    int nwf = NTG * KCH * 512;
    prep_wf<<<(nwf + 255) / 256, 256, 0, stream>>>(W, Wf);
    prep_uf<<<(PKCH * 512 + 255) / 256, 256, 0, stream>>>(U, Uf);
    lstm_persist2<<<NBLK, 256, 0, stream>>>(ids, emb, bl, Wf, Uf, b2, out);
}

// Round 6
// 2845.533 us; speedup vs baseline: 1.7452x; 1.2505x over previous
//
#include <hip/hip_runtime.h>
#include <hip/hip_bf16.h>

// Problem constants
#define NB 1024      // batch
#define NT 120       // seq len
#define NE 50        // embed (A cols 0..49)
#define NH 300       // hidden (A cols 50..349)
#define KCH 11       // K chunks of 32 (K = 352 padded)
#define AST 360      // LDS A-row stride (bf16)
#define ABUFSZ (16 * AST + 32)
#define NTILE 19     // 16-wide col tiles
#define NTG 76       // tile-gate pairs
#define PKCH 10      // preds K chunks
#define NBLK 64      // blocks = 1024 rows / 16
#define NTHREADS 640 // 10 waves: 2 units each (19 tiles + 1 preds unit)

typedef __bf16 bf16_t;
typedef __bf16 bf16x8 __attribute__((ext_vector_type(8)));
typedef float f32x4 __attribute__((ext_vector_type(4)));

__device__ __forceinline__ float sigmoidf_(float x) { return 1.0f / (1.0f + __expf(-x)); }
__device__ __forceinline__ float tanhf_(float x) {
    return 1.0f - 2.0f / (__expf(2.0f * x) + 1.0f);
}

// Fragment-order W (validated round 5): Wf[((tg*KCH + kk)*64 + lane)*8 + j]
//   tg = tile*4 + gate; hc = tile*16 + (lane&15); k = kk*32 + (lane>>4)*8 + j
__global__ void prep_wf(const float* __restrict__ W, bf16_t* __restrict__ Wf) {
    int gid = blockIdx.x * 256 + threadIdx.x;
    if (gid >= NTG * KCH * 512) return;
    int j = gid & 7;
    int lane = (gid >> 3) & 63;
    int kk = (gid >> 9) % KCH;
    int tg = gid / (KCH * 512);
    int m = lane & 15, quad = lane >> 4;
    int ti = tg >> 2, g = tg & 3;
    int hc = ti * 16 + m;
    int k = kk * 32 + quad * 8 + j;
    float v = (k < 350 && hc < NH) ? W[(long)k * 1200 + g * NH + hc] : 0.0f;
    Wf[gid] = (bf16_t)v;
}

// Fragment-order U^T (validated round 5)
__global__ void prep_uf(const float* __restrict__ U, bf16_t* __restrict__ Uf) {
    int gid = blockIdx.x * 256 + threadIdx.x;
    if (gid >= PKCH * 512) return;
    int j = gid & 7;
    int lane = (gid >> 3) & 63;
    int kk = gid >> 9;
    int m = lane & 15, quad = lane >> 4;
    int c = kk * 32 + quad * 8 + j;
    float v = (m < 5 && c < NH) ? U[c * 5 + m] : 0.0f;
    Uf[gid] = (bf16_t)v;
}

// Sync-free persistent LSTM, 64 blocks x 640 threads (10 waves).
// Block owns 16 batch rows for all 120 steps. A ping-pong in LDS:
// row = [x_t(50) | h_{t-1}(300) | pad]; c in VGPRs. 20 work units
// (19 col-tiles + preds) over 10 waves, 2 each. Wave 9 = tile18 + preds +
// x_{t+1} staging. One __syncthreads per step; zero cross-block traffic.
__global__ void __launch_bounds__(NTHREADS, 3) lstm_persist3(
    const int* __restrict__ ids, const float* __restrict__ emb,
    const float* __restrict__ bl, const bf16_t* __restrict__ Wf,
    const bf16_t* __restrict__ Uf, const float* __restrict__ b2,
    float* __restrict__ out)
{
    __shared__ bf16_t Abuf[2 * ABUFSZ];
    __shared__ int idsl[16 * NT];
    const int tid = threadIdx.x, blk = blockIdx.x;
    const int wave = tid >> 6, lane = tid & 63;
    const int m = lane & 15, quad = lane >> 4;
    const int row0 = blk * 16;

    // zero both A buffers; stage ids tile (16 rows x 120 steps) into LDS
    for (int i = tid; i < 2 * ABUFSZ; i += NTHREADS) Abuf[i] = (bf16_t)0.0f;
    for (int i = tid; i < 16 * NT; i += NTHREADS)
        idsl[i] = ids[(row0 + i / NT) * NT + (i % NT)];
    __syncthreads();

    // stage x_0 into buffer 0 (wave 9; 4 lanes per batch row)
    if (wave == 9) {
        int r = lane >> 2, p = lane & 3;
        int id = idsl[r * NT + 0];
        const float* er = emb + (long)id * NE + p * 16;
        bf16_t* d = Abuf + r * AST + p * 16;
        if (p < 3) {
            bf16_t tmp[16];
#pragma unroll
            for (int q = 0; q < 8; ++q) {
                float2 v = ((const float2*)er)[q];
                tmp[2 * q] = (bf16_t)v.x; tmp[2 * q + 1] = (bf16_t)v.y;
            }
            *(bf16x8*)d = *(bf16x8*)tmp;
            *(bf16x8*)(d + 8) = *(bf16x8*)(tmp + 8);
        } else {
            float2 v = *(const float2*)er;   // cols 48,49
            d[0] = (bf16_t)v.x; d[1] = (bf16_t)v.y;
        }
    }
    __syncthreads();

    // per-wave unit setup: units u0 = 2*wave, u1 = 2*wave+1 (19 == preds)
    const int u0 = wave * 2, u1 = wave * 2 + 1;
    const bool hasPred = (u1 == NTILE);     // wave 9
    int colv[2]; bool cok[2]; float bias[2][4]; float creg[2][4];
    const bf16_t* wp[2][4];
#pragma unroll
    for (int s = 0; s < 2; ++s) {
        int u = s ? u1 : u0; if (u > 18) u = 18;
        colv[s] = u * 16 + m;
        cok[s] = (colv[s] < NH) && !(s && hasPred);
#pragma unroll
        for (int g = 0; g < 4; ++g) {
            wp[s][g] = Wf + (long)(u * 4 + g) * (KCH * 512) + lane * 8;
            bias[s][g] = cok[s] ? bl[g * NH + colv[s]] : 0.f;
        }
#pragma unroll
        for (int r = 0; r < 4; ++r) creg[s][r] = 0.f;
    }
    const bf16_t* up = Uf + lane * 8;
    const float pb2 = (m < 5) ? b2[m] : 0.f;

    for (int t = 0; t < NT; ++t) {
        const bf16_t* Ac = Abuf + (t & 1) * ABUFSZ;
        bf16_t* An       = Abuf + ((t + 1) & 1) * ABUFSZ;
        const bf16_t* Arow = Ac + m * AST;

        // A fragments (shared by both units): A[row=m][k=kk*32+quad*8+j]
        bf16x8 af[KCH];
#pragma unroll
        for (int kk = 0; kk < KCH; ++kk)
            af[kk] = *(const bf16x8*)(Arow + kk * 32 + quad * 8);

#pragma unroll
        for (int s = 0; s < 2; ++s) {
            if (s == 1 && hasPred) break;    // wave 9: unit 1 is preds below
            f32x4 acc[4];
#pragma unroll
            for (int g = 0; g < 4; ++g) acc[g] = (f32x4){0.f, 0.f, 0.f, 0.f};
#pragma unroll
            for (int kk = 0; kk < KCH; ++kk) {
#pragma unroll
                for (int g = 0; g < 4; ++g)
                    acc[g] = __builtin_amdgcn_mfma_f32_16x16x32_bf16(
                        af[kk], *(const bf16x8*)(wp[s][g] + kk * 512),
                        acc[g], 0, 0, 0);
            }
            // C/D: col = lane&15, row = quad*4 + r (validated rounds 2-5)
#pragma unroll
            for (int r = 0; r < 4; ++r) {
                float zi = acc[0][r] + bias[s][0];
                float zj = acc[1][r] + bias[s][1];
                float zf = acc[2][r] + bias[s][2];
                float zo = acc[3][r] + bias[s][3];
                float cn = creg[s][r] * sigmoidf_(zf + 1.0f)
                         + sigmoidf_(zi) * tanhf_(zj);
                creg[s][r] = cn;
                float hn = tanhf_(cn) * sigmoidf_(zo);
                if (cok[s])
                    An[(quad * 4 + r) * AST + NE + colv[s]] = (bf16_t)hn;
            }
        }

        if (hasPred) {
            // preds[t-1] = h_{t-1} @ U + b2 (h-region of Ac)
            if (t >= 1) {
                f32x4 pacc = (f32x4){0.f, 0.f, 0.f, 0.f};
#pragma unroll
                for (int kk = 0; kk < PKCH; ++kk) {
                    bf16x8 ah = *(const bf16x8*)(Arow + NE + kk * 32 + quad * 8);
                    pacc = __builtin_amdgcn_mfma_f32_16x16x32_bf16(
                        ah, *(const bf16x8*)(up + kk * 512), pacc, 0, 0, 0);
                }
                if (m < 5) {
                    float* op = out + (long)(t - 1) * (NB * 5)
                              + (row0 + quad * 4) * 5 + m;
                    op[0] = pacc[0] + pb2;  op[5] = pacc[1] + pb2;
                    op[10] = pacc[2] + pb2; op[15] = pacc[3] + pb2;
                }
            }
            // stage x_{t+1} into An's x region (prefetched gather)
            if (t + 1 < NT) {
                int r = lane >> 2, p = lane & 3;
                int id = idsl[r * NT + (t + 1)];
                const float* er = emb + (long)id * NE + p * 16;
                bf16_t* d = An + r * AST + p * 16;
                if (p < 3) {
                    bf16_t tmp[16];
#pragma unroll
                    for (int q = 0; q < 8; ++q) {
                        float2 v = ((const float2*)er)[q];
                        tmp[2 * q] = (bf16_t)v.x; tmp[2 * q + 1] = (bf16_t)v.y;
                    }
                    *(bf16x8*)d = *(bf16x8*)tmp;
                    *(bf16x8*)(d + 8) = *(bf16x8*)(tmp + 8);
                } else {
                    float2 v = *(const float2*)er;
                    d[0] = (bf16_t)v.x; d[1] = (bf16_t)v.y;
                }
            }
        }
        __syncthreads();
    }

    // preds[NT-1] from buffer (NT&1) = buffer 0
    if (hasPred) {
        const bf16_t* Arow = Abuf + (NT & 1) * ABUFSZ + m * AST;
        f32x4 pacc = (f32x4){0.f, 0.f, 0.f, 0.f};
#pragma unroll
        for (int kk = 0; kk < PKCH; ++kk) {
            bf16x8 ah = *(const bf16x8*)(Arow + NE + kk * 32 + quad * 8);
            pacc = __builtin_amdgcn_mfma_f32_16x16x32_bf16(
                ah, *(const bf16x8*)(up + kk * 512), pacc, 0, 0, 0);
        }
        if (m < 5) {
            float* op = out + (long)(NT - 1) * (NB * 5) + (row0 + quad * 4) * 5 + m;
            op[0] = pacc[0] + pb2;  op[5] = pacc[1] + pb2;
            op[10] = pacc[2] + pb2; op[15] = pacc[3] + pb2;
        }
    }
}

extern "C" void kernel_launch(void* const* d_in, const int* in_sizes, int n_in,
                              void* d_out, int out_size, void* d_ws, size_t ws_size,
                              hipStream_t stream) {
    const int* ids   = (const int*)d_in[0];
    const float* emb = (const float*)d_in[1];
    const float* W   = (const float*)d_in[2];
    const float* bl  = (const float*)d_in[3];
    const float* U   = (const float*)d_in[4];
    const float* b2  = (const float*)d_in[5];
    float* out = (float*)d_out;

    // ws: Wf 856,064 B + Uf 10,240 B  (well under proven ws capacity)
    char* ws = (char*)d_ws;
    bf16_t* Wf = (bf16_t*)ws;
    bf16_t* Uf = (bf16_t*)(ws + 856064);

    int nwf = NTG * KCH * 512;
    prep_wf<<<(nwf + 255) / 256, 256, 0, stream>>>(W, Wf);
    prep_uf<<<(PKCH * 512 + 255) / 256, 256, 0, stream>>>(U, Uf);
    lstm_persist3<<<NBLK, NTHREADS, 0, stream>>>(ids, emb, bl, Wf, Uf, b2, out);
}